// Round 7
// baseline (445.326 us; speedup 1.0000x reference)
//
#include <hip/hip_runtime.h>
#include <hip/hip_bf16.h>

// BitLevelMapper: bits [B,16] int32 {0,1} (mem index j holds value bit 15-j),
// tables [16, 32768] float32 {0,1}. For bit i: addr = value of bits 0..i-1,
// flip = tables[i][addr], out bit i = bit i ^ flip. Output float32, reversed
// layout like input.
//
// Live table = sum_i 2^i = 65535 bits ~= 8 KB packed -> LDS.
// R5/R6: split into unidirectional passes via 8 MB intermediate (beat fused
//   163 -> ~140 us total).
// R7: ALL irregular work (table staging, lookups, shuffles) moved into the
//   read-bound transform pass; write pass is stripped to fill-kernel shape
//   (no LDS/sync/table -> pure coalesced float4 stream at ~6.6 TB/s target).

#define PACK_WORDS 2048   // 65536 bits (65535 used), 8 KB

typedef float vfloat4 __attribute__((ext_vector_type(4)));

__global__ __launch_bounds__(256) void
pack_tables_kernel(const float* __restrict__ tables, unsigned* __restrict__ packed) {
    int g = blockIdx.x * blockDim.x + threadIdx.x;   // global bit index
    bool val = false;
    if (g < 65535) {
        int i = 31 - __clz(g + 1);            // row: (2^i - 1) <= g < (2^{i+1} - 1)
        int a = g - ((1 << i) - 1);           // address within row
        val = tables[i * 32768 + a] != 0.0f;
    }
    unsigned long long m = __ballot(val);
    if ((threadIdx.x & 63) == 0) {            // one writer per wave, 2 words
        packed[(g >> 5)]     = (unsigned)m;
        packed[(g >> 5) + 1] = (unsigned)(m >> 32);
    }
}

// Pass A: bits -> final 16-bit output values (8 MB), one ushort per row.
// Lane t&3=q loads quarter q of row t>>2 (coalesced 16 B/lane); quad
// OR-butterfly assembles v; each quad lane does 4 of the 16 table lookups;
// second butterfly combines the partial results; lane q==0 stores r16.
__global__ __launch_bounds__(256) void
transform_kernel(const int4* __restrict__ bits4,
                 const unsigned* __restrict__ packed,
                 unsigned short* __restrict__ rowv, int nquarter) {
    __shared__ unsigned tab[PACK_WORDS];
    {   // stage 8 KB table (512 int4 / 256 threads = 2 each)
        const int4* p4 = (const int4*)packed;
        int4* t4 = (int4*)tab;
        t4[threadIdx.x]       = p4[threadIdx.x];
        t4[threadIdx.x + 256] = p4[threadIdx.x + 256];
    }
    __syncthreads();

    const int q  = threadIdx.x & 3;           // my quarter within the row
    const int t0 = blockIdx.x * 256 + threadIdx.x;
    const int stride = gridDim.x * 256;       // multiple of 4 -> t&3 invariant

    for (int t = t0; t < nquarter; t += stride) {
        int4 m = bits4[t];
        // nibble bit3 = first element in memory order = value bit 15-4q
        unsigned nb = (unsigned)((m.x << 3) | (m.y << 2) | (m.z << 1) | m.w);
        unsigned v  = nb << (12 - (q << 2));
        v |= (unsigned)__shfl_xor((int)v, 1, 64);
        v |= (unsigned)__shfl_xor((int)v, 2, 64);   // all quad lanes: full row value

        // 4 of 16 lookups per lane (i = 4q..4q+3), partial result in r
        unsigned r = 0;
        #pragma unroll
        for (int jj = 0; jj < 4; ++jj) {
            int i = (q << 2) + jj;
            unsigned mask = (1u << i) - 1u;
            unsigned bidx = mask + (v & mask);       // (2^i-1) + addr
            unsigned fl   = tab[bidx >> 5] >> (bidx & 31u);
            r |= (((v >> i) ^ fl) & 1u) << i;
        }
        r |= (unsigned)__shfl_xor((int)r, 1, 64);
        r |= (unsigned)__shfl_xor((int)r, 2, 64);   // full 16-bit output value

        if (q == 0)
            rowv[t >> 2] = (unsigned short)r;
    }
}

// Pass B: fill-shaped expansion. Thread handles 4 quarter-rows (one float4
// store each, lane-contiguous); reads the row's precomputed ushort (L2/L3).
__global__ __launch_bounds__(256) void
expand_kernel(const unsigned short* __restrict__ rowv,
              vfloat4* __restrict__ out4) {
    const size_t base = (size_t)blockIdx.x * 1024 + threadIdx.x;
    const int q4 = (int)(threadIdx.x & 3) << 2;      // 4*q
    #pragma unroll
    for (int it = 0; it < 4; ++it) {
        size_t t = base + (size_t)it * 256;          // quarter index
        unsigned v = rowv[t >> 2];                   // 4 lanes share a row
        vfloat4 f;
        f.x = (float)((v >> (15 - q4)) & 1u);
        f.y = (float)((v >> (14 - q4)) & 1u);
        f.z = (float)((v >> (13 - q4)) & 1u);
        f.w = (float)((v >> (12 - q4)) & 1u);
        out4[t] = f;                                 // plain store (fill-like)
    }
}

extern "C" void kernel_launch(void* const* d_in, const int* in_sizes, int n_in,
                              void* d_out, int out_size, void* d_ws, size_t ws_size,
                              hipStream_t stream) {
    const int*      bits   = (const int*)d_in[0];
    const float*    tables = (const float*)d_in[1];
    float*          out    = (float*)d_out;
    unsigned*       packed = (unsigned*)d_ws;                       // 8 KB
    unsigned short* rowv   = (unsigned short*)((char*)d_ws + 8192); // 8 MB

    int nrows    = in_sizes[0] / 16;       // 4194304
    int nquarter = nrows * 4;              // 16777216

    pack_tables_kernel<<<65536 / 256, 256, 0, stream>>>(tables, packed);

    // grid-stride: 2048 blocks, 32 int4 loads/thread
    transform_kernel<<<2048, 256, 0, stream>>>((const int4*)bits, packed,
                                               rowv, nquarter);

    // 4 quarters/thread -> 1024 quarters/block
    expand_kernel<<<nquarter / 1024, 256, 0, stream>>>(rowv, (vfloat4*)out);
}